// Round 6
// baseline (117271.997 us; speedup 1.0000x reference)
//
#include <hip/hip_runtime.h>
#include <hip/hip_bf16.h>
#include <hip/hip_fp8.h>

#define DEV_INLINE __device__ __forceinline__

typedef __attribute__((ext_vector_type(8))) short bf16x8;
typedef __attribute__((ext_vector_type(4))) float f32x4;
typedef __attribute__((ext_vector_type(2))) float f32x2;
typedef __attribute__((ext_vector_type(4))) unsigned int u32x4;
typedef unsigned long long ull;

// Problem constants
constexpr int Bc = 64, Sc = 512, Dc = 512, Hc = 8, HDc = 64, MELc = 80, Tc = 2560;
constexpr int OUTSTRIDE = Tc * MELc; // 204800

// ---------------- workspace layout (bytes) ----------------
constexpr size_t SZ_KP8 = 64ull * 8 * 512 * 64;         // 16777216 fp8 K[b][h][s][d]
constexpr size_t SZ_VP  = 64ull * 8 * 512 * 64 * 2;     // 33554432 bf16 V[b][h][s][d]
constexpr size_t SZ_PL  = 128ull * 2048 * 16;           // 4194304  packed LSTM cell
constexpr size_t OFF_KP8 = 0;
constexpr size_t OFF_VP  = OFF_KP8 + SZ_KP8;
constexpr size_t OFF_PL0 = OFF_VP + SZ_VP;
constexpr size_t OFF_PL1 = OFF_PL0 + SZ_PL;
constexpr size_t OFF_PL2 = OFF_PL1 + SZ_PL;
constexpr size_t OFF_PWQ = OFF_PL2 + SZ_PL;             // 524288
constexpr size_t OFF_CTR = OFF_PWQ + 524288;            // 81920 (arrival counter lines)
constexpr size_t OFF_BL0 = OFF_CTR + 81920;             // 8192
constexpr size_t OFF_BL1 = OFF_BL0 + 8192;
constexpr size_t OFF_BL2 = OFF_BL1 + 8192;
constexpr size_t OFF_B2E = OFF_BL2 + 8192;              // 8192 (f32 2048)
constexpr size_t OFF_W2E = OFF_B2E + 8192;              // 2097152 (bf16 2048x512)
constexpr size_t OFF_WOT = OFF_W2E + 2097152;           // 1048576 (f32 512x512)
constexpr size_t OFF_ACT = OFF_WOT + 1048576;           // 524288: h10[2],h11[2],h2[2],ctx[2]

constexpr unsigned DYN_LDS = 121088;                    // dynamic LDS carve (see kernel)

// ---------------- helpers ----------------
DEV_INLINE float bf2f(short s) { return __uint_as_float(((unsigned)(unsigned short)s) << 16); }
DEV_INLINE short f2bf(float f) { union { __hip_bfloat16 h; short s; } u; u.h = __float2bfloat16(f); return u.s; }
DEV_INLINE float sig_f(float x) { return 1.0f / (1.0f + __expf(-x)); }
DEV_INLINE float tanh_f(float x) {
  float ax = fabsf(x);
  float e = __expf(fminf(2.0f * ax, 80.0f));
  float r = 1.0f - 2.0f / (e + 1.0f);
  return copysignf(r, x);
}
DEV_INLINE bf16x8 cvt8(const float* p) {
  bf16x8 r;
#pragma unroll
  for (int i = 0; i < 8; ++i) r[i] = f2bf(p[i]);
  return r;
}
DEV_INLINE float fp8tof(unsigned v) {
  __hip_fp8_e4m3 t; t.__x = (__hip_fp8_storage_t)v; return (float)t;
}

// HW packed fp8(e4m3, OCP on gfx950) -> 2xf32; WORD selects bytes [0:1] or [2:3]
template <bool HI>
DEV_INLINE f32x2 cvt2_fp8(unsigned w) {
#if defined(__has_builtin) && __has_builtin(__builtin_amdgcn_cvt_pk_f32_fp8)
  return __builtin_amdgcn_cvt_pk_f32_fp8(w, HI);
#else
  unsigned b = HI ? (w >> 16) : w;
  f32x2 r; r[0] = fp8tof(b & 0xFFu); r[1] = fp8tof((b >> 8) & 0xFFu);
  return r;
#endif
}

// ---- MALL-coherent (agent-scope RELAXED: no cache wb/inv) 8B access ----
DEV_INLINE ull ld_dev_u64(const void* p) {
  return __hip_atomic_load((const ull*)p, __ATOMIC_RELAXED, __HIP_MEMORY_SCOPE_AGENT);
}
DEV_INLINE void st_dev_u64(void* p, ull v) {
  __hip_atomic_store((ull*)p, v, __ATOMIC_RELAXED, __HIP_MEMORY_SCOPE_AGENT);
}
DEV_INLINE bf16x8 ld_frag(const __hip_bfloat16* p) {
  union { bf16x8 v; ull u[2]; } r;
  r.u[0] = ld_dev_u64(p);
  r.u[1] = ld_dev_u64((const char*)p + 8);
  return r.v;
}

// ---------------- setup kernels ----------------
// out = A[M,512] @ Bt[rows][512].T (bf16 MFMA from fp32)
// mode 0: KV bf16 pack [b][h][s][d] + bias; mode 1: row-major bf16 [M,512];
// mode 2: KV fp8-e4m3 pack [b][h][s][d] + bias
__global__ __launch_bounds__(256) void gemm_setup(const float* __restrict__ A,
                                                  const float* __restrict__ Bt,
                                                  const float* __restrict__ bias,
                                                  __hip_bfloat16* __restrict__ dst,
                                                  unsigned char* __restrict__ dst8,
                                                  int mode) {
  int tid = threadIdx.x, lane = tid & 63, wv = tid >> 6;
  int m0 = blockIdx.y * 64 + wv * 16;
  int nb = blockIdx.x * 64;
  int mrow = m0 + (lane & 15);
  int kb = (lane >> 4) * 8;
  f32x4 acc0 = {0,0,0,0}, acc1 = {0,0,0,0}, acc2 = {0,0,0,0}, acc3 = {0,0,0,0};
  const float* arow = A + (size_t)mrow * 512 + kb;
  const float* b0r = Bt + (size_t)(nb + 0 * 16 + (lane & 15)) * 512 + kb;
  const float* b1r = Bt + (size_t)(nb + 1 * 16 + (lane & 15)) * 512 + kb;
  const float* b2r = Bt + (size_t)(nb + 2 * 16 + (lane & 15)) * 512 + kb;
  const float* b3r = Bt + (size_t)(nb + 3 * 16 + (lane & 15)) * 512 + kb;
  for (int kk = 0; kk < 16; ++kk) {
    bf16x8 af = cvt8(arow + kk * 32);
    acc0 = __builtin_amdgcn_mfma_f32_16x16x32_bf16(af, cvt8(b0r + kk * 32), acc0, 0, 0, 0);
    acc1 = __builtin_amdgcn_mfma_f32_16x16x32_bf16(af, cvt8(b1r + kk * 32), acc1, 0, 0, 0);
    acc2 = __builtin_amdgcn_mfma_f32_16x16x32_bf16(af, cvt8(b2r + kk * 32), acc2, 0, 0, 0);
    acc3 = __builtin_amdgcn_mfma_f32_16x16x32_bf16(af, cvt8(b3r + kk * 32), acc3, 0, 0, 0);
  }
  int col16 = lane & 15, r0 = (lane >> 4) * 4;
  f32x4 accs[4] = {acc0, acc1, acc2, acc3};
#pragma unroll
  for (int nt = 0; nt < 4; ++nt) {
    int n = nb + nt * 16 + col16;
#pragma unroll
    for (int r = 0; r < 4; ++r) {
      int m = m0 + r0 + r;
      float v = accs[nt][r];
      if (mode == 0) {
        v += bias[n];
        int bb = m >> 9, s = m & 511, h = n >> 6, d = n & 63;
        dst[(((size_t)(bb * 8 + h) * 512 + s) * 64) + d] = __float2bfloat16(v);
      } else if (mode == 2) {
        v += bias[n];
        int bb = m >> 9, s = m & 511, h = n >> 6, d = n & 63;
        __hip_fp8_e4m3 q(v);
        dst8[(((size_t)(bb * 8 + h) * 512 + s) * 64) + d] = (unsigned char)q.__x;
      } else {
        dst[(size_t)m * 512 + n] = __float2bfloat16(v);
      }
    }
  }
}

__global__ __launch_bounds__(256) void transpose512(const float* __restrict__ in, float* __restrict__ out) {
  __shared__ float tl[32][33];
  int x = threadIdx.x & 31, ty = threadIdx.x >> 5;
  int bx = blockIdx.x * 32, by = blockIdx.y * 32;
#pragma unroll
  for (int r = 0; r < 4; ++r) tl[ty + r * 8][x] = in[(size_t)(by + ty + r * 8) * 512 + bx + x];
  __syncthreads();
#pragma unroll
  for (int r = 0; r < 4; ++r) out[(size_t)(bx + ty + r * 8) * 512 + by + x] = tl[x][ty + r * 8];
}

__global__ __launch_bounds__(256) void b2eff_k(const float* __restrict__ w2ih, const float* __restrict__ bout,
                                               const float* __restrict__ bih, const float* __restrict__ bhh,
                                               float* __restrict__ dst) {
  int g = blockIdx.x * 256 + threadIdx.x;
  float acc = bih[g] + bhh[g];
  const float* row = w2ih + (size_t)g * 512;
  for (int k = 0; k < 512; ++k) acc += row[k] * bout[k];
  dst[g] = acc;
}

// Pack one LSTM cell slice (4 units): col16 = gate*4+unit, K-cat [lo|hi], slot = kk*64+lane
__global__ __launch_bounds__(256) void pack_lstm(const float* __restrict__ lo_f32,
                                                 const __hip_bfloat16* __restrict__ lo_bf16,
                                                 const float* __restrict__ hi_f32,
                                                 const float* __restrict__ b1, const float* __restrict__ b2,
                                                 const float* __restrict__ b_pre,
                                                 __hip_bfloat16* __restrict__ dst, float* __restrict__ bias_out,
                                                 int mode) {
  int u = blockIdx.x, tid = threadIdx.x;
  for (int rep = 0; rep < 8; ++rep) {
    int slot = rep * 256 + tid;            // 0..2047
    int kk = slot >> 6, lane = slot & 63;
    int n16 = lane & 15, gate = n16 >> 2, jj = n16 & 3;
    int srow = gate * 512 + u * 4 + jj;
    int k = kk * 32 + (lane >> 4) * 8;
    __hip_bfloat16 tmp[8];
    if (k < 512) {
      if (mode == 0) {
#pragma unroll
        for (int i = 0; i < 8; ++i) tmp[i] = __float2bfloat16(lo_f32[(size_t)srow * 512 + k + i]);
      } else {
#pragma unroll
        for (int i = 0; i < 8; ++i) tmp[i] = lo_bf16[(size_t)srow * 512 + k + i];
      }
    } else {
#pragma unroll
      for (int i = 0; i < 8; ++i) tmp[i] = __float2bfloat16(hi_f32[(size_t)srow * 512 + (k - 512) + i]);
    }
    *(uint4*)(dst + ((size_t)u * 2048 + slot) * 8) = *(uint4*)tmp;
  }
  if (tid < 16) {
    int gate = tid >> 2, jj = tid & 3;
    int srow = gate * 512 + u * 4 + jj;
    bias_out[u * 16 + tid] = (mode == 0) ? (b1[srow] + b2[srow]) : b_pre[srow];
  }
}

__global__ __launch_bounds__(256) void pack_wq(const float* __restrict__ wq, __hip_bfloat16* __restrict__ dst) {
  int h = blockIdx.x, tid = threadIdx.x;
  for (int rep = 0; rep < 16; ++rep) {
    int slot = rep * 256 + tid;            // nt*1024 + kk*64 + lane
    int nt = slot >> 10, kk = (slot >> 6) & 15, lane = slot & 63;
    int srow = h * 64 + nt * 16 + (lane & 15);
    int k = kk * 32 + (lane >> 4) * 8;
    __hip_bfloat16 tmp[8];
#pragma unroll
    for (int i = 0; i < 8; ++i) tmp[i] = __float2bfloat16(wq[(size_t)srow * 512 + k + i]);
    *(uint4*)(dst + ((size_t)h * 4096 + slot) * 8) = *(uint4*)tmp;
  }
}

// ---------------- main persistent decoder ----------------
struct DecParams {
  const float* attn_in_b;
  const float* proj_b;
  const float* proj_w;
  const uint4* packL0; const uint4* packL1; const uint4* packL2;
  const float* biasL0; const float* biasL1; const float* biasL2;
  const uint4* packWq;
  const unsigned char* Kp8; const __hip_bfloat16* Vp;
  __hip_bfloat16* h10b; __hip_bfloat16* h11b; __hip_bfloat16* h2b; __hip_bfloat16* ctxb;
  ull* actbase;
  unsigned* flags;   // arrival counter lines (monotonic)
  float* out;
};

constexpr ull WD_TICKS = 200000000ull;   // watchdog

// counter layout: line idx (0..127) = ((g*4+s)*2+h)*8 + sub, each on its own
// 128B line (32 dwords). 8 producers per sub-counter -> 8x less same-address
// atomic serialization than a single counter. Line 128 = init barrier.
DEV_INLINE int ctr_idx(int g, int s, int h) { return (((g << 2) + s) * 2 + h) * 8; }

// publish: drain this wave's vmem (stores acked at MALL), join WG, one atomic add
// to this WG's sub-counter line (non-returning).
DEV_INLINE void publish8(unsigned* F, int line, int tid) {
  __builtin_amdgcn_s_waitcnt(0);
  __syncthreads();
  if (tid == 0)
    (void)__hip_atomic_fetch_add(F + line * 32, 1u, __ATOMIC_RELAXED, __HIP_MEMORY_SCOPE_AGENT);
}

// poll 8 sub-counters: lane i polls line idx+(i&7); one wave = one poll round.
DEV_INLINE bool wait8(unsigned* F, int idx, unsigned target, int lane, ull t0, int* sbail) {
  unsigned* p = F + (idx + (lane & 7)) * 32;
  for (;;) {
    unsigned v = __hip_atomic_load(p, __ATOMIC_RELAXED, __HIP_MEMORY_SCOPE_AGENT);
    if (__all(v >= target ? 1 : 0)) return true;
    if (__builtin_amdgcn_s_memrealtime() - t0 > WD_TICKS) { *sbail = 1; return false; }
    __builtin_amdgcn_s_sleep(1);
  }
}

// single-line poll (init/final), branch kept wave-uniform via readfirstlane
DEV_INLINE bool wait_one(unsigned* c, unsigned target, ull t0, int* sbail) {
  for (;;) {
    unsigned v = (unsigned)__builtin_amdgcn_readfirstlane(
        (int)__hip_atomic_load(c, __ATOMIC_RELAXED, __HIP_MEMORY_SCOPE_AGENT));
    if (v >= target) return true;
    if (__builtin_amdgcn_s_memrealtime() - t0 > WD_TICKS) { *sbail = 1; return false; }
    __builtin_amdgcn_s_sleep(1);
  }
}

// prefetch 16 A-fragments of the STALE half (waves 2,3 only)
DEV_INLINE void prefetch_hi(bf16x8* pf, const __hip_bfloat16* hi, int g, int lane, int wv) {
  if (wv >= 2) {
    const __hip_bfloat16* p = hi + (size_t)(g * 32 + (wv & 1) * 16 + (lane & 15)) * 512 + (lane >> 4) * 8;
#pragma unroll
    for (int kk = 0; kk < 16; ++kk) pf[kk] = ld_frag(p + kk * 32);
  }
}

// One LSTM stage for 32 batch rows (group), 4 hidden units (this WG).
// waves: wv = mt + 2*kh (mt = M-tile of 16, kh = K-half). Weights from LDS.
// Dependent (lo) half uses split-half arrival counters: dims [0,256) counted at
// line idx (8 subs), dims [256,512) at line idx+8.
DEV_INLINE bool lstm_stage(int tid, int g, int wgl,
                           const uint4* wlds, const float* bias,
                           const __hip_bfloat16* lo, const bf16x8* pf,
                           float* cstate, __hip_bfloat16* hc,
                           float* pred, ull* st64,
                           unsigned* F, int idx, unsigned target,
                           ull t0, int* sbail) {
  const int lane = tid & 63, wv = tid >> 6, mt = wv & 1, kh = wv >> 1;
  f32x4 acc = {0,0,0,0};
  if (kh == 0) {
    const __hip_bfloat16* pA = lo + (size_t)(g * 32 + mt * 16 + (lane & 15)) * 512 + (lane >> 4) * 8;
    if (wait8(F, idx, target, lane, t0, sbail)) {
#pragma unroll
      for (int kk = 0; kk < 8; ++kk) {
        bf16x8 a = ld_frag(pA + kk * 32);
        bf16x8 b = *(const bf16x8*)(wlds + kk * 64 + lane);
        acc = __builtin_amdgcn_mfma_f32_16x16x32_bf16(a, b, acc, 0, 0, 0);
      }
      if (wait8(F, idx + 8, target, lane, t0, sbail)) {
#pragma unroll
        for (int kk = 8; kk < 16; ++kk) {
          bf16x8 a = ld_frag(pA + kk * 32);
          bf16x8 b = *(const bf16x8*)(wlds + kk * 64 + lane);
          acc = __builtin_amdgcn_mfma_f32_16x16x32_bf16(a, b, acc, 0, 0, 0);
        }
      }
    }
  } else {
#pragma unroll
    for (int kk = 0; kk < 16; ++kk) {
      bf16x8 b = *(const bf16x8*)(wlds + (16 + kk) * 64 + lane);
      acc = __builtin_amdgcn_mfma_f32_16x16x32_bf16(pf[kk], b, acc, 0, 0, 0);
    }
  }
#pragma unroll
  for (int r = 0; r < 4; ++r) pred[wv * 256 + lane * 4 + r] = acc[r];
  __syncthreads();
  if (*sbail) return false;
  if (tid < 128) {
    int bl = tid >> 2, j = tid & 3;
    int mt2 = bl >> 4, qd = (bl & 15) >> 2, reg = bl & 3;
    const float* p0 = pred + mt2 * 256;
    const float* p1 = pred + (2 + mt2) * 256;
    int l0 = qd * 16;
    float gi = p0[(l0 + j) * 4 + reg]      + p1[(l0 + j) * 4 + reg]      + bias[j];
    float gf = p0[(l0 + 4 + j) * 4 + reg]  + p1[(l0 + 4 + j) * 4 + reg]  + bias[4 + j];
    float gg = p0[(l0 + 8 + j) * 4 + reg]  + p1[(l0 + 8 + j) * 4 + reg]  + bias[8 + j];
    float go = p0[(l0 + 12 + j) * 4 + reg] + p1[(l0 + 12 + j) * 4 + reg] + bias[12 + j];
    float c = cstate[tid & 127];
    c = sig_f(gf) * c + sig_f(gi) * tanh_f(gg);
    float h = sig_f(go) * tanh_f(c);
    cstate[tid & 127] = c;
    ((unsigned short*)st64)[tid] = (unsigned short)f2bf(h);
  }
  __syncthreads();
  if (tid < 32)
    st_dev_u64(hc + (size_t)(g * 32 + tid) * 512 + wgl * 4, st64[tid]);
  return true;
}

// spread projection: each WG computes 20 (batch,mel) dot products with VALU +
// wave shuffle-reduce. Uniform ~0.2us across all 128 WGs -> no stragglers.
DEV_INLINE void proj_spread(int tid, int g, int wgl, const float* pw, const float* pb,
                            const __hip_bfloat16* h2in, float* outp) {
  const int lane = tid & 63, pr = tid >> 6;
#pragma unroll
  for (int r = 0; r < 5; ++r) {
    int P = wgl * 20 + r * 4 + pr;       // 0..2559
    int b = P / 80, m = P - b * 80;
    bf16x8 hv = ld_frag(h2in + (size_t)(g * 32 + b) * 512 + lane * 8);
    const f32x4* w4 = (const f32x4*)(pw + (size_t)m * 512 + lane * 8);
    f32x4 wa = w4[0], wb = w4[1];
    float acc = bf2f(hv[0]) * wa[0] + bf2f(hv[1]) * wa[1] + bf2f(hv[2]) * wa[2] + bf2f(hv[3]) * wa[3]
              + bf2f(hv[4]) * wb[0] + bf2f(hv[5]) * wb[1] + bf2f(hv[6]) * wb[2] + bf2f(hv[7]) * wb[3];
#pragma unroll
    for (int off = 32; off; off >>= 1) acc += __shfl_xor(acc, off);
    if (lane == 0) outp[(size_t)(g * 32 + b) * OUTSTRIDE + m] = acc + pb[m];
  }
}

__global__ __launch_bounds__(256, 1) void decoder_main(DecParams P) {
  extern __shared__ char smem[];
  uint4* wL0 = (uint4*)smem;                         // 32768 B
  uint4* wL1 = wL0 + 2048;                           // 32768
  uint4* wL2 = wL1 + 2048;                           // 32768
  ull*   st64 = (ull*)(wL2 + 2048);                  // 256
  float* pred = (float*)(st64 + 32);                 // 4096
  float* qls  = pred + 1024;                         // 4352 (16x68)
  float* sco  = qls + 1088;                          // 4096 (2x512)
  float* red  = sco + 1024;                          // 8192 (2x16x64)
  float* cst  = red + 2048;                          // 1536 (3x128)
  float* smx  = cst + 384;
  float* ssum = smx + 4;
  float* sinv = ssum + 4;
  int*   sbail = (int*)(sinv + 2);

  const int wg = blockIdx.x, tid = threadIdx.x;
  const int lane = tid & 63, wv = tid >> 6;
  const int g = wg >> 7;            // group 0/1 (batches g*32..g*32+31)
  const int wgl = wg & 127;         // unit slice within group
  const int myhalf = wgl >> 6;      // producer half for counters
  const int mysub = (wgl >> 3) & 7; // sub-counter within half (8 producers each)
  const int hh = wgl >> 4;          // head for attention
  const int b0g = (wgl & 15) * 2;   // group-local batch pair base
  const int bblk = b0g & ~15;       // 16-batch block for q-MFMA

  const ull t0 = __builtin_amdgcn_s_memrealtime();
  unsigned* F = P.flags;

  // ---- stage weights into LDS ----
  {
    const uint4* s0 = P.packL0 + (size_t)wgl * 2048;
    const uint4* s1 = P.packL1 + (size_t)wgl * 2048;
    const uint4* s2 = P.packL2 + (size_t)wgl * 2048;
    for (int i = tid; i < 2048; i += 256) { wL0[i] = s0[i]; wL1[i] = s1[i]; wL2[i] = s2[i]; }
  }
  if (tid == 0) *sbail = 0;
  if (tid < 128) { cst[tid] = 0.0f; cst[128 + tid] = 0.0f; cst[256 + tid] = 0.0f; }
  // zero activation buffers coherently (MALL holds poison otherwise)
  st_dev_u64(P.actbase + (size_t)wg * 256 + tid, 0ull);
  __syncthreads();
  publish8(F, 128, tid);                     // init barrier line, target 256
  if (!wait_one(F + 128 * 32, 256u, t0, sbail)) goto bail;
  __syncthreads();

  for (int t = 0; t < Tc; ++t) {
    const int cur = t & 1, pv = cur ^ 1;
    const unsigned tgtP = 8u * (unsigned)t;        // prev-step stage D arrivals/sub
    const unsigned tgtC = 8u * (unsigned)(t + 1);  // current-step arrivals/sub
    __hip_bfloat16* h10c = P.h10b + cur * 32768; __hip_bfloat16* h10p = P.h10b + pv * 32768;
    __hip_bfloat16* h11c = P.h11b + cur * 32768; __hip_bfloat16* h11p = P.h11b + pv * 32768;
    __hip_bfloat16* h2c  = P.h2b  + cur * 32768; __hip_bfloat16* h2p  = P.h2b  + pv * 32768;
    __hip_bfloat16* ctxc = P.ctxb + cur * 32768;

    // ---- stage A: LSTM0  in=[h2p | h10p] ----
    {
      bf16x8 pf[16];
      prefetch_hi(pf, h10p, g, lane, wv);           // stale half, certified last step
      if (!lstm_stage(tid, g, wgl, wL0, P.biasL0 + wgl * 16, h2p, pf, cst, h10c, pred, st64,
                      F, ctr_idx(g, 3, 0), tgtP, t0, sbail)) goto bail;
      publish8(F, ctr_idx(g, 0, myhalf) + mysub, tid);
    }
    // projection for t-1 (spread over ALL WGs; h2p is certified by stage A's waits)
    if (t > 0)
      proj_spread(tid, g, wgl, P.proj_w, P.proj_b, h2p, P.out + (size_t)(t - 1) * MELc);

    // ---- stage B: LSTM1  in=[h10c | h11p] ----
    {
      bf16x8 pf[16];
      prefetch_hi(pf, h11p, g, lane, wv);
      if (!lstm_stage(tid, g, wgl, wL1, P.biasL1 + wgl * 16, h10c, pf, cst + 128, h11c, pred, st64,
                      F, ctr_idx(g, 0, 0), tgtC, t0, sbail)) goto bail;
      publish8(F, ctr_idx(g, 1, myhalf) + mysub, tid);
    }

    // V prefetch registers (PV mapping) — filled during scores phase below
    ull va0[16], va1[16], vb0[16], vb1[16];

    // ---- stage C: attention (2 (b,h) pairs per WG) ----
    {
      // q for the 16-batch block, this head (4 waves = 4 col tiles); split-half arrival wait
      int mrow = g * 32 + bblk + (lane & 15);
      const __hip_bfloat16* pA = h11c + (size_t)mrow * 512 + (lane >> 4) * 8;
      const uint4* pB = P.packWq + (size_t)hh * 4096 + wv * 1024;
      f32x4 acc = {0,0,0,0};
      if (wait8(F, ctr_idx(g, 1, 0), tgtC, lane, t0, sbail)) {
#pragma unroll
        for (int kk = 0; kk < 8; ++kk) {
          bf16x8 a = ld_frag(pA + kk * 32);
          bf16x8 b = *(const bf16x8*)(pB + kk * 64 + lane);
          acc = __builtin_amdgcn_mfma_f32_16x16x32_bf16(a, b, acc, 0, 0, 0);
        }
        if (wait8(F, ctr_idx(g, 1, 1), tgtC, lane, t0, sbail)) {
#pragma unroll
          for (int kk = 8; kk < 16; ++kk) {
            bf16x8 a = ld_frag(pA + kk * 32);
            bf16x8 b = *(const bf16x8*)(pB + kk * 64 + lane);
            acc = __builtin_amdgcn_mfma_f32_16x16x32_bf16(a, b, acc, 0, 0, 0);
          }
        }
      }
      int col = lane & 15, row0 = (lane >> 4) << 2;
      int dg = wv * 16 + col;
      float bq = P.attn_in_b[hh * 64 + dg];
#pragma unroll
      for (int r = 0; r < 4; ++r) qls[(row0 + r) * 68 + dg] = (acc[r] + bq) * 0.125f;
    }
    __syncthreads();
    if (*sbail) goto bail;
    {
      // scores: 2 pairs x 512 positions, fp8 K (L2-resident; V bypasses L2 so K stays)
      // q preloaded to registers once (position-invariant), HW pk-cvt, packed FMA.
      int p = tid >> 7, si = tid & 127;
      int bg = g * 32 + b0g + p;
      const float* qv = qls + ((b0g & 15) + p) * 68;
      f32x4 q4[16];
#pragma unroll
      for (int i = 0; i < 16; ++i) q4[i] = *(const f32x4*)(qv + 4 * i);
      const u32x4* Kb = (const u32x4*)(P.Kp8 + (size_t)(bg * 8 + hh) * 512 * 64);
#pragma unroll
      for (int ss = 0; ss < 4; ++ss) {
        int s = si * 4 + ss;
        const u32x4* kr = Kb + s * 4;
        f32x2 acc2 = {0.0f, 0.0f};
#pragma unroll
        for (int i = 0; i < 4; ++i) {
          u32x4 kv = kr[i];
#pragma unroll
          for (int j = 0; j < 4; ++j) {
            unsigned w = kv[j];
            f32x2 c01 = cvt2_fp8<false>(w);   // dims 16i+4j+0,1
            f32x2 c23 = cvt2_fp8<true>(w);    // dims 16i+4j+2,3
            f32x4 qq = q4[i * 4 + j];
            acc2 += c01 * (f32x2){qq[0], qq[1]} + c23 * (f32x2){qq[2], qq[3]};
          }
        }
        sco[p * 512 + s] = acc2[0] + acc2[1];
      }
      // issue ALL V loads now (addresses static, PV mapping): softmax (no vmem)
      // covers the MALL RT, so PV runs with data already in registers.
      {
        int pp = wv >> 1, hf = wv & 1;
        int bgp = g * 32 + b0g + pp;
        int sg = lane >> 3, dj = lane & 7;
        const char* Vb = (const char*)(P.Vp + (size_t)(bgp * 8 + hh) * 512 * 64);
        const int s0v = hf * 256 + sg;
#pragma unroll
        for (int it = 0; it < 16; ++it) {
          const char* pa = Vb + (size_t)(s0v + it * 8) * 128 + dj * 16;
          const char* pq = Vb + (size_t)(s0v + it * 8 + 128) * 128 + dj * 16;
          va0[it] = ld_dev_u64(pa); va1[it] = ld_dev_u64(pa + 8);
          vb0[it] = ld_dev_u64(pq); vb1[it] = ld_dev_u64(pq + 8);
        }
        asm volatile("" ::: "memory");   // pin issue point (don't sink into PV)
      }
    }
    __syncthreads();
    {
      // softmax (unnormalized exp + 1/sum)
      int p = wv >> 1, half = wv & 1;
      int idx = tid & 127;
      float mx = -1e30f;
#pragma unroll
      for (int ss = 0; ss < 4; ++ss) mx = fmaxf(mx, sco[p * 512 + idx * 4 + ss]);
#pragma unroll
      for (int off = 32; off; off >>= 1) mx = fmaxf(mx, __shfl_xor(mx, off));
      if (lane == 0) smx[p * 2 + half] = mx;
      __syncthreads();
      float m = fmaxf(smx[p * 2], smx[p * 2 + 1]);
      float sum = 0.0f;
#pragma unroll
      for (int ss = 0; ss < 4; ++ss) {
        int ix = p * 512 + idx * 4 + ss;
        float e = __expf(sco[ix] - m);
        sco[ix] = e; sum += e;
      }
#pragma unroll
      for (int off = 32; off; off >>= 1) sum += __shfl_xor(sum, off);
      if (lane == 0) ssum[p * 2 + half] = sum;
      __syncthreads();
      if (tid < 2) sinv[tid] = 1.0f / (ssum[tid * 2] + ssum[tid * 2 + 1]);
    }
    __syncthreads();
    {
      // ctx = softmax . V : V already in registers (prefetched during scores),
      // pure VALU now — no exposed MALL latency.
      int p = wv >> 1, half = wv & 1;
      int sg = lane >> 3, dj = lane & 7;
      f32x2 aA[4] = {{0,0},{0,0},{0,0},{0,0}};
      f32x2 aB[4] = {{0,0},{0,0},{0,0},{0,0}};
      const int s0 = half * 256 + sg;
#pragma unroll
      for (int it = 0; it < 16; ++it) {
        int sA = s0 + it * 8, sB = sA + 128;
        float wa = sco[p * 512 + sA], wb = sco[p * 512 + sB];
        f32x2 wA = {wa, wa}, wB = {wb, wb};
        unsigned va[4] = {(unsigned)va0[it], (unsigned)(va0[it] >> 32),
                          (unsigned)va1[it], (unsigned)(va1[it] >> 32)};
        unsigned vb[4] = {(unsigned)vb0[it], (unsigned)(vb0[it] >> 32),
                          (unsigned)vb1[it], (unsigned)(vb1[it] >> 32)};
#pragma unroll
        for (int j = 0; j < 4; ++j) {
          f32x2 fa = { __uint_as_float(va[j] << 16), __uint_as_float(va[j] & 0xFFFF0000u) };
          f32x2 fb = { __uint_as_float(vb[j] << 16), __uint_as_float(vb[j] & 0xFFFF0000u) };
          aA[j] += wA * fa;
          aB[j] += wB * fb;
        }
      }
      float* rp = red + ((p * 16 + half * 8 + sg) * 64) + dj * 8;
#pragma unroll
      for (int j = 0; j < 4; ++j) {
        rp[j * 2]     = aA[j][0] + aB[j][0];
        rp[j * 2 + 1] = aA[j][1] + aB[j][1];
      }
    }
    __syncthreads();
    if (tid < 128) {
      int p = tid >> 6, d = tid & 63;
      float sacc = 0.0f;
#pragma unroll
      for (int k = 0; k < 16; ++k) sacc += red[(p * 16 + k) * 64 + d];
      sacc *= sinv[p];
      ((unsigned short*)st64)[tid] = (unsigned short)f2bf(sacc);
    }
    __syncthreads();
    if (tid < 32) {
      int p = tid >> 4, q = tid & 15;
      st_dev_u64(ctxc + (size_t)(g * 32 + b0g + p) * 512 + hh * 64 + q * 4, st64[p * 16 + q]);
    }
    publish8(F, ctr_idx(g, 2, myhalf) + mysub, tid);

    // ---- stage D: LSTM2  in=[ctxc | h2p] (out-proj folded) ----
    {
      bf16x8 pf[16];
      prefetch_hi(pf, h2p, g, lane, wv);
      if (!lstm_stage(tid, g, wgl, wL2, P.biasL2 + wgl * 16, ctxc, pf, cst + 256, h2c, pred, st64,
                      F, ctr_idx(g, 2, 0), tgtC, t0, sbail)) goto bail;
      publish8(F, ctr_idx(g, 3, myhalf) + mysub, tid);
    }
  }

  // final projection for t = Tc-1 (wait for both h2 halves of this group, then spread)
  if (wait8(F, ctr_idx(g, 3, 0), 8u * Tc, lane, t0, sbail) &&
      wait8(F, ctr_idx(g, 3, 1), 8u * Tc, lane, t0, sbail)) {
    __syncthreads();
    proj_spread(tid, g, wgl, P.proj_w, P.proj_b, P.h2b + ((Tc - 1) & 1) * 32768,
                P.out + (size_t)(Tc - 1) * MELc);
  }
  return;

bail:
  // unlock everyone: make every counter line exceed any reachable target
  if (tid == 0)
    for (int i = 0; i <= 128; ++i)
      (void)__hip_atomic_fetch_add(F + i * 32, 1u << 20, __ATOMIC_RELAXED, __HIP_MEMORY_SCOPE_AGENT);
}

// ---------------- launcher ----------------
extern "C" void kernel_launch(void* const* d_in, const int* in_sizes, int n_in,
                              void* d_out, int out_size, void* d_ws, size_t ws_size,
                              hipStream_t stream) {
  const float* enc        = (const float*)d_in[0];
  const float* attn_in_w  = (const float*)d_in[1];
  const float* attn_in_b  = (const float*)d_in[2];
  const float* attn_out_w = (const float*)d_in[3];
  const float* attn_out_b = (const float*)d_in[4];
  const float* w_ih0 = (const float*)d_in[5];
  const float* w_hh0 = (const float*)d_in[6];
  const float* b_ih0 = (const float*)d_in[7];
  const float* b_hh0 = (const float*)d_in[8];
  const float* w_ih1 = (const float*)d_in[9];
  const float* w_hh1 = (const float*)d_in[10];
  const float* b_ih1 = (const float*)d_in[11];
  const float* b_hh1 = (const float*)d_in[12];
  const float* w_ih2 = (const float*)d_in[13];
  const float* w_hh2 = (const float*)d_in[14];
  const float* b_ih2 = (const float*)d_in[15];
  const float* b_hh2 = (const float*)d_in[16];
  const float* proj_w = (const float*)d_in[17];
  const float* proj_b = (const float*)d_in[18];

  char* ws = (char*)d_ws;
  unsigned char*  Kp8 = (unsigned char*)(ws + OFF_KP8);
  __hip_bfloat16* Vp  = (__hip_bfloat16*)(ws + OFF_VP);
  __hip_bfloat16* pl0 = (__hip_bfloat16*)(ws + OFF_PL0);
  __hip_bfloat16* pl1 = (__hip_bfloat16*)(ws + OFF_PL1);
  __hip_bfloat16* pl2 = (__hip_bfloat16*)(ws + OFF_PL2);
  __hip_bfloat16* pwq = (__hip_bfloat16*)(ws + OFF_PWQ);
  float* bl0 = (float*)(ws + OFF_BL0);
  float* bl1 = (float*)(ws + OFF_BL1);
  float* bl2 = (float*)(ws + OFF_BL2);
  float* b2e = (float*)(ws + OFF_B2E);
  __hip_bfloat16* w2e = (__hip_bfloat16*)(ws + OFF_W2E);
  float* wot = (float*)(ws + OFF_WOT);
  char* act  = ws + OFF_ACT;
  unsigned* ctrs = (unsigned*)(ws + OFF_CTR);

  hipMemsetAsync(ctrs, 0, 20480, stream);   // 129 counter lines x 128B

  // K (fp8 e4m3) and V (bf16), packed [b][h][s][d]
  gemm_setup<<<dim3(8, 512), 256, 0, stream>>>(enc, attn_in_w + 512 * 512, attn_in_b + 512, nullptr, Kp8, 2);
  gemm_setup<<<dim3(8, 512), 256, 0, stream>>>(enc, attn_in_w + 1024 * 512, attn_in_b + 1024, Vp, nullptr, 0);
  // W2eff = W2ih @ Wout
  transpose512<<<dim3(16, 16), 256, 0, stream>>>(attn_out_w, wot);
  gemm_setup<<<dim3(8, 32), 256, 0, stream>>>(w_ih2, wot, nullptr, w2e, nullptr, 1);
  b2eff_k<<<8, 256, 0, stream>>>(w_ih2, attn_out_b, b_ih2, b_hh2, b2e);
  // fragment packing
  pack_lstm<<<128, 256, 0, stream>>>(w_ih0, nullptr, w_hh0, b_ih0, b_hh0, nullptr, pl0, bl0, 0);
  pack_lstm<<<128, 256, 0, stream>>>(w_ih1, nullptr, w_hh1, b_ih1, b_hh1, nullptr, pl1, bl1, 0);
  pack_lstm<<<128, 256, 0, stream>>>(nullptr, w2e, w_hh2, nullptr, nullptr, b2e, pl2, bl2, 1);
  pack_wq<<<8, 256, 0, stream>>>(attn_in_w, pwq);

  DecParams p;
  p.attn_in_b = attn_in_b;
  p.proj_b = proj_b;
  p.proj_w = proj_w;
  p.packL0 = (const uint4*)pl0; p.packL1 = (const uint4*)pl1; p.packL2 = (const uint4*)pl2;
  p.biasL0 = bl0; p.biasL1 = bl1; p.biasL2 = bl2;
  p.packWq = (const uint4*)pwq;
  p.Kp8 = Kp8; p.Vp = Vp;
  p.h10b = (__hip_bfloat16*)(act + 0);
  p.h11b = (__hip_bfloat16*)(act + 131072);
  p.h2b  = (__hip_bfloat16*)(act + 262144);
  p.ctxb = (__hip_bfloat16*)(act + 393216);
  p.actbase = (ull*)act;
  p.flags = ctrs;
  p.out = (float*)d_out;

  // allow >64KB dynamic LDS (no-op if unsupported)
  (void)hipFuncSetAttribute((const void*)decoder_main,
                            hipFuncAttributeMaxDynamicSharedMemorySize, DYN_LDS);
  decoder_main<<<dim3(256), dim3(256), DYN_LDS, stream>>>(p);
}

// Round 8
// 94362.195 us; speedup vs baseline: 1.2428x; 1.2428x over previous
//
#include <hip/hip_runtime.h>
#include <hip/hip_bf16.h>
#include <hip/hip_fp8.h>

#define DEV_INLINE __device__ __forceinline__

typedef __attribute__((ext_vector_type(8))) short bf16x8;
typedef __attribute__((ext_vector_type(4))) float f32x4;
typedef __attribute__((ext_vector_type(2))) float f32x2;
typedef __attribute__((ext_vector_type(4))) unsigned int u32x4;
typedef unsigned long long ull;

// Problem constants
constexpr int Bc = 64, Sc = 512, Dc = 512, Hc = 8, HDc = 64, MELc = 80, Tc = 2560;
constexpr int OUTSTRIDE = Tc * MELc; // 204800

// ---------------- workspace layout (bytes) ----------------
constexpr size_t SZ_KP8 = 64ull * 8 * 512 * 64;         // 16777216 fp8 K[b][h][s][d]
constexpr size_t SZ_VP  = 64ull * 8 * 512 * 64 * 2;     // 33554432 bf16 V[b][h][s][d]
constexpr size_t SZ_PL  = 128ull * 2048 * 16;           // 4194304  packed LSTM cell
constexpr size_t OFF_KP8 = 0;
constexpr size_t OFF_VP  = OFF_KP8 + SZ_KP8;
constexpr size_t OFF_PL0 = OFF_VP + SZ_VP;
constexpr size_t OFF_PL1 = OFF_PL0 + SZ_PL;
constexpr size_t OFF_PL2 = OFF_PL1 + SZ_PL;
constexpr size_t OFF_PWQ = OFF_PL2 + SZ_PL;             // 524288
constexpr size_t OFF_CTR = OFF_PWQ + 524288;            // 81920 (arrival counter lines)
constexpr size_t OFF_BL0 = OFF_CTR + 81920;             // 8192
constexpr size_t OFF_BL1 = OFF_BL0 + 8192;
constexpr size_t OFF_BL2 = OFF_BL1 + 8192;
constexpr size_t OFF_B2E = OFF_BL2 + 8192;              // 8192 (f32 2048)
constexpr size_t OFF_W2E = OFF_B2E + 8192;              // 2097152 (bf16 2048x512)
constexpr size_t OFF_WOT = OFF_W2E + 2097152;           // 1048576 (f32 512x512)
constexpr size_t OFF_ACT = OFF_WOT + 1048576;           // 524288: h10[2],h11[2],h2[2],ctx[2]

constexpr unsigned DYN_LDS = 121088;                    // dynamic LDS carve (see kernel)

// ---------------- helpers ----------------
DEV_INLINE float bf2f(short s) { return __uint_as_float(((unsigned)(unsigned short)s) << 16); }
DEV_INLINE short f2bf(float f) { union { __hip_bfloat16 h; short s; } u; u.h = __float2bfloat16(f); return u.s; }
DEV_INLINE float sig_f(float x) { return 1.0f / (1.0f + __expf(-x)); }
DEV_INLINE float tanh_f(float x) {
  float ax = fabsf(x);
  float e = __expf(fminf(2.0f * ax, 80.0f));
  float r = 1.0f - 2.0f / (e + 1.0f);
  return copysignf(r, x);
}
DEV_INLINE bf16x8 cvt8(const float* p) {
  bf16x8 r;
#pragma unroll
  for (int i = 0; i < 8; ++i) r[i] = f2bf(p[i]);
  return r;
}
DEV_INLINE float fp8tof(unsigned v) {
  __hip_fp8_e4m3 t; t.__x = (__hip_fp8_storage_t)v; return (float)t;
}

// HW packed fp8(e4m3, OCP on gfx950) -> 2xf32; WORD selects bytes [0:1] or [2:3]
template <bool HI>
DEV_INLINE f32x2 cvt2_fp8(unsigned w) {
#if defined(__has_builtin) && __has_builtin(__builtin_amdgcn_cvt_pk_f32_fp8)
  return __builtin_amdgcn_cvt_pk_f32_fp8(w, HI);
#else
  unsigned b = HI ? (w >> 16) : w;
  f32x2 r; r[0] = fp8tof(b & 0xFFu); r[1] = fp8tof((b >> 8) & 0xFFu);
  return r;
#endif
}

// ---- MALL-coherent (agent-scope RELAXED: no cache wb/inv) 8B access ----
DEV_INLINE ull ld_dev_u64(const void* p) {
  return __hip_atomic_load((const ull*)p, __ATOMIC_RELAXED, __HIP_MEMORY_SCOPE_AGENT);
}
DEV_INLINE void st_dev_u64(void* p, ull v) {
  __hip_atomic_store((ull*)p, v, __ATOMIC_RELAXED, __HIP_MEMORY_SCOPE_AGENT);
}
DEV_INLINE bf16x8 ld_frag(const __hip_bfloat16* p) {
  union { bf16x8 v; ull u[2]; } r;
  r.u[0] = ld_dev_u64(p);
  r.u[1] = ld_dev_u64((const char*)p + 8);
  return r.v;
}

// ---------------- setup kernels ----------------
// out = A[M,512] @ Bt[rows][512].T (bf16 MFMA from fp32)
// mode 0: KV bf16 pack [b][h][s][d] + bias; mode 1: row-major bf16 [M,512];
// mode 2: KV fp8-e4m3 pack [b][h][s][d] + bias
__global__ __launch_bounds__(256) void gemm_setup(const float* __restrict__ A,
                                                  const float* __restrict__ Bt,
                                                  const float* __restrict__ bias,
                                                  __hip_bfloat16* __restrict__ dst,
                                                  unsigned char* __restrict__ dst8,
                                                  int mode) {
  int tid = threadIdx.x, lane = tid & 63, wv = tid >> 6;
  int m0 = blockIdx.y * 64 + wv * 16;
  int nb = blockIdx.x * 64;
  int mrow = m0 + (lane & 15);
  int kb = (lane >> 4) * 8;
  f32x4 acc0 = {0,0,0,0}, acc1 = {0,0,0,0}, acc2 = {0,0,0,0}, acc3 = {0,0,0,0};
  const float* arow = A + (size_t)mrow * 512 + kb;
  const float* b0r = Bt + (size_t)(nb + 0 * 16 + (lane & 15)) * 512 + kb;
  const float* b1r = Bt + (size_t)(nb + 1 * 16 + (lane & 15)) * 512 + kb;
  const float* b2r = Bt + (size_t)(nb + 2 * 16 + (lane & 15)) * 512 + kb;
  const float* b3r = Bt + (size_t)(nb + 3 * 16 + (lane & 15)) * 512 + kb;
  for (int kk = 0; kk < 16; ++kk) {
    bf16x8 af = cvt8(arow + kk * 32);
    acc0 = __builtin_amdgcn_mfma_f32_16x16x32_bf16(af, cvt8(b0r + kk * 32), acc0, 0, 0, 0);
    acc1 = __builtin_amdgcn_mfma_f32_16x16x32_bf16(af, cvt8(b1r + kk * 32), acc1, 0, 0, 0);
    acc2 = __builtin_amdgcn_mfma_f32_16x16x32_bf16(af, cvt8(b2r + kk * 32), acc2, 0, 0, 0);
    acc3 = __builtin_amdgcn_mfma_f32_16x16x32_bf16(af, cvt8(b3r + kk * 32), acc3, 0, 0, 0);
  }
  int col16 = lane & 15, r0 = (lane >> 4) * 4;
  f32x4 accs[4] = {acc0, acc1, acc2, acc3};
#pragma unroll
  for (int nt = 0; nt < 4; ++nt) {
    int n = nb + nt * 16 + col16;
#pragma unroll
    for (int r = 0; r < 4; ++r) {
      int m = m0 + r0 + r;
      float v = accs[nt][r];
      if (mode == 0) {
        v += bias[n];
        int bb = m >> 9, s = m & 511, h = n >> 6, d = n & 63;
        dst[(((size_t)(bb * 8 + h) * 512 + s) * 64) + d] = __float2bfloat16(v);
      } else if (mode == 2) {
        v += bias[n];
        int bb = m >> 9, s = m & 511, h = n >> 6, d = n & 63;
        __hip_fp8_e4m3 q(v);
        dst8[(((size_t)(bb * 8 + h) * 512 + s) * 64) + d] = (unsigned char)q.__x;
      } else {
        dst[(size_t)m * 512 + n] = __float2bfloat16(v);
      }
    }
  }
}

__global__ __launch_bounds__(256) void transpose512(const float* __restrict__ in, float* __restrict__ out) {
  __shared__ float tl[32][33];
  int x = threadIdx.x & 31, ty = threadIdx.x >> 5;
  int bx = blockIdx.x * 32, by = blockIdx.y * 32;
#pragma unroll
  for (int r = 0; r < 4; ++r) tl[ty + r * 8][x] = in[(size_t)(by + ty + r * 8) * 512 + bx + x];
  __syncthreads();
#pragma unroll
  for (int r = 0; r < 4; ++r) out[(size_t)(bx + ty + r * 8) * 512 + by + x] = tl[x][ty + r * 8];
}

__global__ __launch_bounds__(256) void b2eff_k(const float* __restrict__ w2ih, const float* __restrict__ bout,
                                               const float* __restrict__ bih, const float* __restrict__ bhh,
                                               float* __restrict__ dst) {
  int g = blockIdx.x * 256 + threadIdx.x;
  float acc = bih[g] + bhh[g];
  const float* row = w2ih + (size_t)g * 512;
  for (int k = 0; k < 512; ++k) acc += row[k] * bout[k];
  dst[g] = acc;
}

// Pack one LSTM cell slice (4 units): col16 = gate*4+unit, K-cat [lo|hi], slot = kk*64+lane
__global__ __launch_bounds__(256) void pack_lstm(const float* __restrict__ lo_f32,
                                                 const __hip_bfloat16* __restrict__ lo_bf16,
                                                 const float* __restrict__ hi_f32,
                                                 const float* __restrict__ b1, const float* __restrict__ b2,
                                                 const float* __restrict__ b_pre,
                                                 __hip_bfloat16* __restrict__ dst, float* __restrict__ bias_out,
                                                 int mode) {
  int u = blockIdx.x, tid = threadIdx.x;
  for (int rep = 0; rep < 8; ++rep) {
    int slot = rep * 256 + tid;            // 0..2047
    int kk = slot >> 6, lane = slot & 63;
    int n16 = lane & 15, gate = n16 >> 2, jj = n16 & 3;
    int srow = gate * 512 + u * 4 + jj;
    int k = kk * 32 + (lane >> 4) * 8;
    __hip_bfloat16 tmp[8];
    if (k < 512) {
      if (mode == 0) {
#pragma unroll
        for (int i = 0; i < 8; ++i) tmp[i] = __float2bfloat16(lo_f32[(size_t)srow * 512 + k + i]);
      } else {
#pragma unroll
        for (int i = 0; i < 8; ++i) tmp[i] = lo_bf16[(size_t)srow * 512 + k + i];
      }
    } else {
#pragma unroll
      for (int i = 0; i < 8; ++i) tmp[i] = __float2bfloat16(hi_f32[(size_t)srow * 512 + (k - 512) + i]);
    }
    *(uint4*)(dst + ((size_t)u * 2048 + slot) * 8) = *(uint4*)tmp;
  }
  if (tid < 16) {
    int gate = tid >> 2, jj = tid & 3;
    int srow = gate * 512 + u * 4 + jj;
    bias_out[u * 16 + tid] = (mode == 0) ? (b1[srow] + b2[srow]) : b_pre[srow];
  }
}

__global__ __launch_bounds__(256) void pack_wq(const float* __restrict__ wq, __hip_bfloat16* __restrict__ dst) {
  int h = blockIdx.x, tid = threadIdx.x;
  for (int rep = 0; rep < 16; ++rep) {
    int slot = rep * 256 + tid;            // nt*1024 + kk*64 + lane
    int nt = slot >> 10, kk = (slot >> 6) & 15, lane = slot & 63;
    int srow = h * 64 + nt * 16 + (lane & 15);
    int k = kk * 32 + (lane >> 4) * 8;
    __hip_bfloat16 tmp[8];
#pragma unroll
    for (int i = 0; i < 8; ++i) tmp[i] = __float2bfloat16(wq[(size_t)srow * 512 + k + i]);
    *(uint4*)(dst + ((size_t)h * 4096 + slot) * 8) = *(uint4*)tmp;
  }
}

// ---------------- main persistent decoder ----------------
struct DecParams {
  const float* attn_in_b;
  const float* proj_b;
  const float* proj_w;
  const uint4* packL0; const uint4* packL1; const uint4* packL2;
  const float* biasL0; const float* biasL1; const float* biasL2;
  const uint4* packWq;
  const unsigned char* Kp8; const __hip_bfloat16* Vp;
  __hip_bfloat16* h10b; __hip_bfloat16* h11b; __hip_bfloat16* h2b; __hip_bfloat16* ctxb;
  ull* actbase;
  unsigned* flags;   // arrival counter lines (monotonic)
  float* out;
};

constexpr ull WD_TICKS = 200000000ull;   // watchdog (absolute deadline; bounded runtime)

// counter layout: line idx (0..127) = ((g*4+s)*2+h)*8 + sub, each on its own
// 128B line (32 dwords). 8 producers per sub-counter -> 8x less same-address
// atomic serialization than a single counter. Line 128 = init barrier.
DEV_INLINE int ctr_idx(int g, int s, int h) { return (((g << 2) + s) * 2 + h) * 8; }

// publish: drain this wave's vmem (stores acked at MALL), join WG, one atomic add
// to this WG's sub-counter line (non-returning).
DEV_INLINE void publish8(unsigned* F, int line, int tid) {
  __builtin_amdgcn_s_waitcnt(0);
  __syncthreads();
  if (tid == 0)
    (void)__hip_atomic_fetch_add(F + line * 32, 1u, __ATOMIC_RELAXED, __HIP_MEMORY_SCOPE_AGENT);
}

// poll 8 sub-counters: lane i polls line idx+(i&7); one wave = one poll round.
DEV_INLINE bool wait8(unsigned* F, int idx, unsigned target, int lane, ull t0, int* sbail) {
  unsigned* p = F + (idx + (lane & 7)) * 32;
  for (;;) {
    unsigned v = __hip_atomic_load(p, __ATOMIC_RELAXED, __HIP_MEMORY_SCOPE_AGENT);
    if (__all(v >= target ? 1 : 0)) return true;
    if (__builtin_amdgcn_s_memrealtime() - t0 > WD_TICKS) { *sbail = 1; return false; }
    __builtin_amdgcn_s_sleep(1);
  }
}

// single-line poll (init/final), branch kept wave-uniform via readfirstlane
DEV_INLINE bool wait_one(unsigned* c, unsigned target, ull t0, int* sbail) {
  for (;;) {
    unsigned v = (unsigned)__builtin_amdgcn_readfirstlane(
        (int)__hip_atomic_load(c, __ATOMIC_RELAXED, __HIP_MEMORY_SCOPE_AGENT));
    if (v >= target) return true;
    if (__builtin_amdgcn_s_memrealtime() - t0 > WD_TICKS) { *sbail = 1; return false; }
    __builtin_amdgcn_s_sleep(1);
  }
}

// One LSTM stage for 32 batch rows (group), 4 hidden units (this WG).
// Stale/fresh-rebalanced: each wave (mt = wv&1 output row-tile, h = wv>>1 K-slice)
// does 8 STALE MFMAs first (no wait — covers producer arrival + discovery RT),
// then waits on its fresh half's sub-counters and does 8 FRESH MFMAs.
// pred reduction unchanged: waves (mt,0)+(mt,1) together cover all 32 K-rows.
// Certification of per-wave split waits: every stale read at step t was observed
// by the SAME wave via a counter >= target at step t-1 (A: stage-B wait on
// ctr(g,0,h); B: stage-C both-half waits; D: this step's stage-A wait on ctr(g,3,h)).
DEV_INLINE bool lstm_stage(int tid, int g, int wgl,
                           const uint4* wlds, const float* bias,
                           const __hip_bfloat16* lo, const __hip_bfloat16* hi,
                           float* cstate, __hip_bfloat16* hc,
                           float* pred, ull* st64,
                           unsigned* F, int idx, unsigned target,
                           ull t0, int* sbail) {
  const int lane = tid & 63, wv = tid >> 6, mt = wv & 1, h = wv >> 1;
  const size_t rowoff = (size_t)(g * 32 + mt * 16 + (lane & 15)) * 512 + (lane >> 4) * 8 + h * 256;
  // issue stale loads (certified last step; no wait needed)
  bf16x8 pf[8];
  {
    const __hip_bfloat16* ph = hi + rowoff;
#pragma unroll
    for (int kk = 0; kk < 8; ++kk) pf[kk] = ld_frag(ph + kk * 32);
  }
  f32x4 acc = {0,0,0,0};
#pragma unroll
  for (int kk = 0; kk < 8; ++kk) {
    bf16x8 b = *(const bf16x8*)(wlds + (16 + h * 8 + kk) * 64 + lane);
    acc = __builtin_amdgcn_mfma_f32_16x16x32_bf16(pf[kk], b, acc, 0, 0, 0);
  }
  // fresh half h: producers half h -> sub-counters idx + h*8
  if (wait8(F, idx + h * 8, target, lane, t0, sbail)) {
    const __hip_bfloat16* pA = lo + rowoff;
#pragma unroll
    for (int kk = 0; kk < 8; ++kk) {
      bf16x8 a = ld_frag(pA + kk * 32);
      bf16x8 b = *(const bf16x8*)(wlds + (h * 8 + kk) * 64 + lane);
      acc = __builtin_amdgcn_mfma_f32_16x16x32_bf16(a, b, acc, 0, 0, 0);
    }
  }
#pragma unroll
  for (int r = 0; r < 4; ++r) pred[wv * 256 + lane * 4 + r] = acc[r];
  __syncthreads();
  if (*sbail) return false;
  if (tid < 128) {
    int bl = tid >> 2, j = tid & 3;
    int mt2 = bl >> 4, qd = (bl & 15) >> 2, reg = bl & 3;
    const float* p0 = pred + mt2 * 256;
    const float* p1 = pred + (2 + mt2) * 256;
    int l0 = qd * 16;
    float gi = p0[(l0 + j) * 4 + reg]      + p1[(l0 + j) * 4 + reg]      + bias[j];
    float gf = p0[(l0 + 4 + j) * 4 + reg]  + p1[(l0 + 4 + j) * 4 + reg]  + bias[4 + j];
    float gg = p0[(l0 + 8 + j) * 4 + reg]  + p1[(l0 + 8 + j) * 4 + reg]  + bias[8 + j];
    float go = p0[(l0 + 12 + j) * 4 + reg] + p1[(l0 + 12 + j) * 4 + reg] + bias[12 + j];
    float c = cstate[tid & 127];
    c = sig_f(gf) * c + sig_f(gi) * tanh_f(gg);
    float h2 = sig_f(go) * tanh_f(c);
    cstate[tid & 127] = c;
    ((unsigned short*)st64)[tid] = (unsigned short)f2bf(h2);
  }
  __syncthreads();
  if (tid < 32)
    st_dev_u64(hc + (size_t)(g * 32 + tid) * 512 + wgl * 4, st64[tid]);
  return true;
}

// spread projection: each WG computes 20 (batch,mel) dot products with VALU +
// wave shuffle-reduce. Uniform ~0.2us across all 128 WGs -> no stragglers.
DEV_INLINE void proj_spread(int tid, int g, int wgl, const float* pw, const float* pb,
                            const __hip_bfloat16* h2in, float* outp) {
  const int lane = tid & 63, pr = tid >> 6;
#pragma unroll
  for (int r = 0; r < 5; ++r) {
    int P = wgl * 20 + r * 4 + pr;       // 0..2559
    int b = P / 80, m = P - b * 80;
    bf16x8 hv = ld_frag(h2in + (size_t)(g * 32 + b) * 512 + lane * 8);
    const f32x4* w4 = (const f32x4*)(pw + (size_t)m * 512 + lane * 8);
    f32x4 wa = w4[0], wb = w4[1];
    float acc = bf2f(hv[0]) * wa[0] + bf2f(hv[1]) * wa[1] + bf2f(hv[2]) * wa[2] + bf2f(hv[3]) * wa[3]
              + bf2f(hv[4]) * wb[0] + bf2f(hv[5]) * wb[1] + bf2f(hv[6]) * wb[2] + bf2f(hv[7]) * wb[3];
#pragma unroll
    for (int off = 32; off; off >>= 1) acc += __shfl_xor(acc, off);
    if (lane == 0) outp[(size_t)(g * 32 + b) * OUTSTRIDE + m] = acc + pb[m];
  }
}

__global__ __launch_bounds__(256, 1) void decoder_main(DecParams P) {
  extern __shared__ char smem[];
  uint4* wL0 = (uint4*)smem;                         // 32768 B
  uint4* wL1 = wL0 + 2048;                           // 32768
  uint4* wL2 = wL1 + 2048;                           // 32768
  ull*   st64 = (ull*)(wL2 + 2048);                  // 256
  float* pred = (float*)(st64 + 32);                 // 4096
  float* qls  = pred + 1024;                         // 4352 (16x68)
  float* sco  = qls + 1088;                          // 4096 (2x512)
  float* red  = sco + 1024;                          // 8192 (2x16x64)
  float* cst  = red + 2048;                          // 1536 (3x128)
  float* smx  = cst + 384;
  float* ssum = smx + 4;
  float* sinv = ssum + 4;
  int*   sbail = (int*)(sinv + 2);

  const int wg = blockIdx.x, tid = threadIdx.x;
  const int lane = tid & 63, wv = tid >> 6;
  const int g = wg >> 7;            // group 0/1 (batches g*32..g*32+31)
  const int wgl = wg & 127;         // unit slice within group
  const int myhalf = wgl >> 6;      // producer half for counters
  const int mysub = (wgl >> 3) & 7; // sub-counter within half (8 producers each)
  const int hh = wgl >> 4;          // head for attention
  const int b0g = (wgl & 15) * 2;   // group-local batch pair base
  const int bblk = b0g & ~15;       // 16-batch block for q-MFMA

  const ull t0 = __builtin_amdgcn_s_memrealtime();
  unsigned* F = P.flags;

  // ---- stage weights into LDS ----
  {
    const uint4* s0 = P.packL0 + (size_t)wgl * 2048;
    const uint4* s1 = P.packL1 + (size_t)wgl * 2048;
    const uint4* s2 = P.packL2 + (size_t)wgl * 2048;
    for (int i = tid; i < 2048; i += 256) { wL0[i] = s0[i]; wL1[i] = s1[i]; wL2[i] = s2[i]; }
  }
  if (tid == 0) *sbail = 0;
  if (tid < 128) { cst[tid] = 0.0f; cst[128 + tid] = 0.0f; cst[256 + tid] = 0.0f; }
  // zero activation buffers coherently (MALL holds poison otherwise)
  st_dev_u64(P.actbase + (size_t)wg * 256 + tid, 0ull);
  __syncthreads();
  publish8(F, 128, tid);                     // init barrier line, target 256
  if (!wait_one(F + 128 * 32, 256u, t0, sbail)) goto bail;
  __syncthreads();

  for (int t = 0; t < Tc; ++t) {
    const int cur = t & 1, pv = cur ^ 1;
    const unsigned tgtP = 8u * (unsigned)t;        // prev-step stage D arrivals/sub
    const unsigned tgtC = 8u * (unsigned)(t + 1);  // current-step arrivals/sub
    __hip_bfloat16* h10c = P.h10b + cur * 32768; __hip_bfloat16* h10p = P.h10b + pv * 32768;
    __hip_bfloat16* h11c = P.h11b + cur * 32768; __hip_bfloat16* h11p = P.h11b + pv * 32768;
    __hip_bfloat16* h2c  = P.h2b  + cur * 32768; __hip_bfloat16* h2p  = P.h2b  + pv * 32768;
    __hip_bfloat16* ctxc = P.ctxb + cur * 32768;

    // ---- stage A: LSTM0  in=[h2p | h10p] ----
    if (!lstm_stage(tid, g, wgl, wL0, P.biasL0 + wgl * 16, h2p, h10p, cst, h10c, pred, st64,
                    F, ctr_idx(g, 3, 0), tgtP, t0, sbail)) goto bail;
    publish8(F, ctr_idx(g, 0, myhalf) + mysub, tid);
    // projection for t-1 (spread over ALL WGs; h2p is certified by stage A's waits)
    if (t > 0)
      proj_spread(tid, g, wgl, P.proj_w, P.proj_b, h2p, P.out + (size_t)(t - 1) * MELc);

    // ---- stage B: LSTM1  in=[h10c | h11p] ----
    if (!lstm_stage(tid, g, wgl, wL1, P.biasL1 + wgl * 16, h10c, h11p, cst + 128, h11c, pred, st64,
                    F, ctr_idx(g, 0, 0), tgtC, t0, sbail)) goto bail;
    publish8(F, ctr_idx(g, 1, myhalf) + mysub, tid);

    // ---- stage C: attention (2 (b,h) pairs per WG) ----
    {
      // q for the 16-batch block, this head (4 waves = 4 col tiles); split-half arrival wait
      int mrow = g * 32 + bblk + (lane & 15);
      const __hip_bfloat16* pA = h11c + (size_t)mrow * 512 + (lane >> 4) * 8;
      const uint4* pB = P.packWq + (size_t)hh * 4096 + wv * 1024;
      f32x4 acc = {0,0,0,0};
      if (wait8(F, ctr_idx(g, 1, 0), tgtC, lane, t0, sbail)) {
#pragma unroll
        for (int kk = 0; kk < 8; ++kk) {
          bf16x8 a = ld_frag(pA + kk * 32);
          bf16x8 b = *(const bf16x8*)(pB + kk * 64 + lane);
          acc = __builtin_amdgcn_mfma_f32_16x16x32_bf16(a, b, acc, 0, 0, 0);
        }
        if (wait8(F, ctr_idx(g, 1, 1), tgtC, lane, t0, sbail)) {
#pragma unroll
          for (int kk = 8; kk < 16; ++kk) {
            bf16x8 a = ld_frag(pA + kk * 32);
            bf16x8 b = *(const bf16x8*)(pB + kk * 64 + lane);
            acc = __builtin_amdgcn_mfma_f32_16x16x32_bf16(a, b, acc, 0, 0, 0);
          }
        }
      }
      int col = lane & 15, row0 = (lane >> 4) << 2;
      int dg = wv * 16 + col;
      float bq = P.attn_in_b[hh * 64 + dg];
#pragma unroll
      for (int r = 0; r < 4; ++r) qls[(row0 + r) * 68 + dg] = (acc[r] + bq) * 0.125f;
    }
    __syncthreads();
    if (*sbail) goto bail;
    {
      // scores: 2 pairs x 512 positions, fp8 K (L2-resident; V bypasses L2 so K stays)
      // q preloaded to registers once (position-invariant), HW pk-cvt, packed FMA.
      int p = tid >> 7, si = tid & 127;
      int bg = g * 32 + b0g + p;
      const float* qv = qls + ((b0g & 15) + p) * 68;
      f32x4 q4[16];
#pragma unroll
      for (int i = 0; i < 16; ++i) q4[i] = *(const f32x4*)(qv + 4 * i);
      const u32x4* Kb = (const u32x4*)(P.Kp8 + (size_t)(bg * 8 + hh) * 512 * 64);
#pragma unroll
      for (int ss = 0; ss < 4; ++ss) {
        int s = si * 4 + ss;
        const u32x4* kr = Kb + s * 4;
        f32x2 acc2 = {0.0f, 0.0f};
#pragma unroll
        for (int i = 0; i < 4; ++i) {
          u32x4 kv = kr[i];
#pragma unroll
          for (int j = 0; j < 4; ++j) {
            unsigned w = kv[j];
            f32x2 c01 = cvt2_fp8<false>(w);   // dims 16i+4j+0,1
            f32x2 c23 = cvt2_fp8<true>(w);    // dims 16i+4j+2,3
            f32x4 qq = q4[i * 4 + j];
            acc2 += c01 * (f32x2){qq[0], qq[1]} + c23 * (f32x2){qq[2], qq[3]};
          }
        }
        sco[p * 512 + s] = acc2[0] + acc2[1];
      }
    }
    __syncthreads();
    {
      // softmax (unnormalized exp + 1/sum)
      int p = wv >> 1, half = wv & 1;
      int idx = tid & 127;
      float mx = -1e30f;
#pragma unroll
      for (int ss = 0; ss < 4; ++ss) mx = fmaxf(mx, sco[p * 512 + idx * 4 + ss]);
#pragma unroll
      for (int off = 32; off; off >>= 1) mx = fmaxf(mx, __shfl_xor(mx, off));
      if (lane == 0) smx[p * 2 + half] = mx;
      __syncthreads();
      float m = fmaxf(smx[p * 2], smx[p * 2 + 1]);
      float sum = 0.0f;
#pragma unroll
      for (int ss = 0; ss < 4; ++ss) {
        int ix = p * 512 + idx * 4 + ss;
        float e = __expf(sco[ix] - m);
        sco[ix] = e; sum += e;
      }
#pragma unroll
      for (int off = 32; off; off >>= 1) sum += __shfl_xor(sum, off);
      if (lane == 0) ssum[p * 2 + half] = sum;
      __syncthreads();
      if (tid < 2) sinv[tid] = 1.0f / (ssum[tid * 2] + ssum[tid * 2 + 1]);
    }
    __syncthreads();
    {
      // ctx = softmax . V : dual independent position chains per thread,
      // agent-scope 8B V loads (bypass L1/L2 -> K keeps L2; V stays MALL-resident),
      // unroll 8 for deep memory-level parallelism against MALL latency.
      int p = wv >> 1, half = wv & 1;
      int bg = g * 32 + b0g + p;
      int sg = lane >> 3, dj = lane & 7;
      const char* Vb = (const char*)(P.Vp + (size_t)(bg * 8 + hh) * 512 * 64);
      f32x2 aA[4] = {{0,0},{0,0},{0,0},{0,0}};
      f32x2 aB[4] = {{0,0},{0,0},{0,0},{0,0}};
      const int s0 = half * 256 + sg;
#pragma unroll 8
      for (int it = 0; it < 16; ++it) {
        int sA = s0 + it * 8, sB = sA + 128;
        const char* pa = Vb + (size_t)sA * 128 + dj * 16;
        const char* pq = Vb + (size_t)sB * 128 + dj * 16;
        ull a0 = ld_dev_u64(pa), a1 = ld_dev_u64(pa + 8);
        ull b0 = ld_dev_u64(pq), b1 = ld_dev_u64(pq + 8);
        float wa = sco[p * 512 + sA], wb = sco[p * 512 + sB];
        f32x2 wA = {wa, wa}, wB = {wb, wb};
        unsigned va[4] = {(unsigned)a0, (unsigned)(a0 >> 32), (unsigned)a1, (unsigned)(a1 >> 32)};
        unsigned vb[4] = {(unsigned)b0, (unsigned)(b0 >> 32), (unsigned)b1, (unsigned)(b1 >> 32)};
#pragma unroll
        for (int j = 0; j < 4; ++j) {
          f32x2 fa = { __uint_as_float(va[j] << 16), __uint_as_float(va[j] & 0xFFFF0000u) };
          f32x2 fb = { __uint_as_float(vb[j] << 16), __uint_as_float(vb[j] & 0xFFFF0000u) };
          aA[j] += wA * fa;
          aB[j] += wB * fb;
        }
      }
      float* rp = red + ((p * 16 + half * 8 + sg) * 64) + dj * 8;
#pragma unroll
      for (int j = 0; j < 4; ++j) {
        rp[j * 2]     = aA[j][0] + aB[j][0];
        rp[j * 2 + 1] = aA[j][1] + aB[j][1];
      }
    }
    __syncthreads();
    if (tid < 128) {
      int p = tid >> 6, d = tid & 63;
      float sacc = 0.0f;
#pragma unroll
      for (int k = 0; k < 16; ++k) sacc += red[(p * 16 + k) * 64 + d];
      sacc *= sinv[p];
      ((unsigned short*)st64)[tid] = (unsigned short)f2bf(sacc);
    }
    __syncthreads();
    if (tid < 32) {
      int p = tid >> 4, q = tid & 15;
      st_dev_u64(ctxc + (size_t)(g * 32 + b0g + p) * 512 + hh * 64 + q * 4, st64[p * 16 + q]);
    }
    publish8(F, ctr_idx(g, 2, myhalf) + mysub, tid);

    // ---- stage D: LSTM2  in=[ctxc | h2p] (out-proj folded) ----
    if (!lstm_stage(tid, g, wgl, wL2, P.biasL2 + wgl * 16, ctxc, h2p, cst + 256, h2c, pred, st64,
                    F, ctr_idx(g, 2, 0), tgtC, t0, sbail)) goto bail;
    publish8(F, ctr_idx(g, 3, myhalf) + mysub, tid);
  }

  // final projection for t = Tc-1 (wait for both h2 halves of this group, then spread)
  if (wait8(F, ctr_idx(g, 3, 0), 8u * Tc, lane, t0, sbail) &&
      wait8(F, ctr_idx(g, 3, 1), 8u * Tc, lane, t0, sbail)) {
    __syncthreads();
    proj_spread(tid, g, wgl, P.proj_w, P.proj_b, P.h2b + ((Tc - 1) & 1) * 32768,
                P.out + (size_t)(Tc - 1) * MELc);
  }
  return;

bail:
  // unlock everyone: make every counter line exceed any reachable target
  if (tid == 0)
    for (int i = 0; i <= 128; ++i)
      (void)__hip_atomic_fetch_add(F + i * 32, 1u << 20, __ATOMIC_RELAXED, __HIP_MEMORY_SCOPE_AGENT);
}

// ---------------- launcher ----------------
extern "C" void kernel_launch(void* const* d_in, const int* in_sizes, int n_in,
                              void* d_out, int out_size, void* d_ws, size_t ws_size,
                              hipStream_t stream) {
  const float* enc        = (const float*)d_in[0];
  const float* attn_in_w  = (const float*)d_in[1];
  const float* attn_in_b  = (const float*)d_in[2];
  const float* attn_out_w = (const float*)d_in[3];
  const float* attn_out_b = (const float*)d_in[4];
  const float* w_ih0 = (const float*)d_in[5];
  const float* w_hh0 = (const float*)d_in[6];
  const float* b_ih0 = (const float*)d_in[7];
  const float* b_hh0 = (const float*)d_in[8];
  const float* w_ih1 = (const float*)d_in[9];
  const float* w_hh1 = (const float*)d_in[10];
  const float* b_ih1 = (const float*)d_in[11];
  const float* b_hh1 = (const float*)d_in[12];
  const float* w_ih2 = (const float*)d_in[13];
  const float* w_hh2 = (const float*)d_in[14];
  const float* b_ih2 = (const float*)d_in[15];
  const float* b_hh2 = (const float*)d_in[16];
  const float* proj_w = (const float*)d_in[17];
  const float* proj_b = (const float*)d_in[18];

  char* ws = (char*)d_ws;
  unsigned char*  Kp8 = (unsigned char*)(ws + OFF_KP8);
  __hip_bfloat16* Vp  = (__hip_bfloat16*)(ws + OFF_VP);
  __hip_bfloat16* pl0 = (__hip_bfloat16*)(ws + OFF_PL0);
  __hip_bfloat16* pl1 = (__hip_bfloat16*)(ws + OFF_PL1);
  __hip_bfloat16* pl2 = (__hip_bfloat16*)(ws + OFF_PL2);
  __hip_bfloat16* pwq = (__hip_bfloat16*)(ws + OFF_PWQ);
  float* bl0 = (float*)(ws + OFF_BL0);
  float* bl1 = (float*)(ws + OFF_BL1);
  float* bl2 = (float*)(ws + OFF_BL2);
  float* b2e = (float*)(ws + OFF_B2E);
  __hip_bfloat16* w2e = (__hip_bfloat16*)(ws + OFF_W2E);
  float* wot = (float*)(ws + OFF_WOT);
  char* act  = ws + OFF_ACT;
  unsigned* ctrs = (unsigned*)(ws + OFF_CTR);

  hipMemsetAsync(ctrs, 0, 20480, stream);   // 129 counter lines x 128B

  // K (fp8 e4m3) and V (bf16), packed [b][h][s][d]
  gemm_setup<<<dim3(8, 512), 256, 0, stream>>>(enc, attn_in_w + 512 * 512, attn_in_b + 512, nullptr, Kp8, 2);
  gemm_setup<<<dim3(8, 512), 256, 0, stream>>>(enc, attn_in_w + 1024 * 512, attn_in_b + 1024, Vp, nullptr, 0);
  // W2eff = W2ih @ Wout
  transpose512<<<dim3(16, 16), 256, 0, stream>>>(attn_out_w, wot);
  gemm_setup<<<dim3(8, 32), 256, 0, stream>>>(w_ih2, wot, nullptr, w2e, nullptr, 1);
  b2eff_k<<<8, 256, 0, stream>>>(w_ih2, attn_out_b, b_ih2, b_hh2, b2e);
  // fragment packing
  pack_lstm<<<128, 256, 0, stream>>>(w_ih0, nullptr, w_hh0, b_ih0, b_hh0, nullptr, pl0, bl0, 0);
  pack_lstm<<<128, 256, 0, stream>>>(w_ih1, nullptr, w_hh1, b_ih1, b_hh1, nullptr, pl1, bl1, 0);
  pack_lstm<<<128, 256, 0, stream>>>(nullptr, w2e, w_hh2, nullptr, nullptr, b2e, pl2, bl2, 1);
  pack_wq<<<8, 256, 0, stream>>>(attn_in_w, pwq);

  DecParams p;
  p.attn_in_b = attn_in_b;
  p.proj_b = proj_b;
  p.proj_w = proj_w;
  p.packL0 = (const uint4*)pl0; p.packL1 = (const uint4*)pl1; p.packL2 = (const uint4*)pl2;
  p.biasL0 = bl0; p.biasL1 = bl1; p.biasL2 = bl2;
  p.packWq = (const uint4*)pwq;
  p.Kp8 = Kp8; p.Vp = Vp;
  p.h10b = (__hip_bfloat16*)(act + 0);
  p.h11b = (__hip_bfloat16*)(act + 131072);
  p.h2b  = (__hip_bfloat16*)(act + 262144);
  p.ctxb = (__hip_bfloat16*)(act + 393216);
  p.actbase = (ull*)act;
  p.flags = ctrs;
  p.out = (float*)d_out;

  // allow >64KB dynamic LDS (no-op if unsupported)
  (void)hipFuncSetAttribute((const void*)decoder_main,
                            hipFuncAttributeMaxDynamicSharedMemorySize, DYN_LDS);
  decoder_main<<<dim3(256), dim3(256), DYN_LDS, stream>>>(p);
}